// Round 1
// baseline (413.750 us; speedup 1.0000x reference)
//
#include <hip/hip_runtime.h>

#define HD 4096
#define NB 64

typedef __attribute__((ext_vector_type(4))) float f32x4;
typedef __attribute__((ext_vector_type(8))) short bf16x8;
typedef __attribute__((ext_vector_type(4))) short s16x4;

__device__ __forceinline__ short f2bf(float f) {
    unsigned u = __float_as_uint(f);
    u += 0x7fffu + ((u >> 16) & 1u);   // round-to-nearest-even (finite inputs)
    return (short)(u >> 16);
}

__device__ __forceinline__ bf16x8 cvt8(f32x4 lo, f32x4 hi) {
    bf16x8 r;
    r[0] = f2bf(lo[0]); r[1] = f2bf(lo[1]); r[2] = f2bf(lo[2]); r[3] = f2bf(lo[3]);
    r[4] = f2bf(hi[0]); r[5] = f2bf(hi[1]); r[6] = f2bf(hi[2]); r[7] = f2bf(hi[3]);
    return r;
}

__device__ __forceinline__ float sigmoidf_(float x) { return 1.f / (1.f + __expf(-x)); }

// ---------------------------------------------------------------------------
// Pre-convert fp32 activations -> bf16 (A operands for the MFMA GEMMs).
// X: 262144 floats, h0: 524288 floats. Grid 768x256, float4 per thread.
// ---------------------------------------------------------------------------
__global__ void convert_kernel(const float* __restrict__ X, const float* __restrict__ h0,
                               short* __restrict__ Xbf, short* __restrict__ H0bf)
{
    const int i = blockIdx.x * blockDim.x + threadIdx.x;
    if (i < 65536) {
        f32x4 v = ((const f32x4*)X)[i];
        s16x4 o = { f2bf(v[0]), f2bf(v[1]), f2bf(v[2]), f2bf(v[3]) };
        ((s16x4*)Xbf)[i] = o;
    } else {
        const int j = i - 65536;
        f32x4 v = ((const f32x4*)h0)[j];
        s16x4 o = { f2bf(v[0]), f2bf(v[1]), f2bf(v[2]), f2bf(v[3]) };
        ((s16x4*)H0bf)[j] = o;
    }
}

// ---------------------------------------------------------------------------
// Fused LSTM layer: gates = A0 @ Wih^T + A1 @ Whh^T + bih + bhh, then cell.
// grid 256 blocks x 256 threads. Block b owns h-columns [b*16, b*16+16).
// Wave w computes gate w (W rows w*4096 + hc0 .. +16) over full K (2x4096).
// W fragments stream straight from global (fp32 -> bf16 in regs, no LDS).
// Epilogue: LDS exchange of i/f/g/o -> LSTM cell -> h,c (+ bf16 h for next GEMM).
// ---------------------------------------------------------------------------
__global__ __launch_bounds__(256, 1) void lstm_layer_kernel(
    const short* __restrict__ Abf0, const short* __restrict__ Abf1,
    const float* __restrict__ Wih, const float* __restrict__ Whh,
    const float* __restrict__ bih, const float* __restrict__ bhh,
    const float* __restrict__ cprev,
    float* __restrict__ hout, float* __restrict__ cout,
    float* __restrict__ hout2, short* __restrict__ hbf)
{
    const int tid  = threadIdx.x;
    const int lane = tid & 63;
    const int wv   = tid >> 6;        // gate index 0..3 (i,f,g,o)
    const int ar   = lane & 15;       // fragment row (A: batch row, B: W row/out col)
    const int kg   = lane >> 4;       // k-group 0..3, 8 elems each
    const int hc0  = blockIdx.x * 16;

    const long jrow = (long)wv * HD + hc0 + ar;
    const short* aSrc[2] = { Abf0 + (long)ar * HD + kg * 8, Abf1 + (long)ar * HD + kg * 8 };
    const float* wSrc[2] = { Wih + jrow * HD + kg * 8,      Whh + jrow * HD + kg * 8 };

    const f32x4 zero = {0.f, 0.f, 0.f, 0.f};
    f32x4 acc[4] = {zero, zero, zero, zero};   // 4 M-frags x (16x16 D tile)

    for (int s = 0; s < 2; ++s) {
        const short* pa = aSrc[s];
        const float* pw = wSrc[s];
        bf16x8 a[2][4][2];
        f32x4  w[2][2][2];

        // prologue: k-step 0
        #pragma unroll
        for (int m = 0; m < 4; ++m)
            #pragma unroll
            for (int ks = 0; ks < 2; ++ks)
                a[0][m][ks] = *(const bf16x8*)(pa + m * 16 * HD + ks * 32);
        #pragma unroll
        for (int ks = 0; ks < 2; ++ks) {
            w[0][ks][0] = *(const f32x4*)(pw + ks * 32);
            w[0][ks][1] = *(const f32x4*)(pw + ks * 32 + 4);
        }

        #pragma unroll 2
        for (int t = 0; t < 64; ++t) {          // K = 4096 in steps of 64
            const int cur = t & 1, nxt = cur ^ 1;
            if (t < 63) {                       // register double-buffer prefetch
                const int ko = (t + 1) * 64;
                #pragma unroll
                for (int m = 0; m < 4; ++m)
                    #pragma unroll
                    for (int ks = 0; ks < 2; ++ks)
                        a[nxt][m][ks] = *(const bf16x8*)(pa + m * 16 * HD + ko + ks * 32);
                #pragma unroll
                for (int ks = 0; ks < 2; ++ks) {
                    w[nxt][ks][0] = *(const f32x4*)(pw + ko + ks * 32);
                    w[nxt][ks][1] = *(const f32x4*)(pw + ko + ks * 32 + 4);
                }
            }
            #pragma unroll
            for (int ks = 0; ks < 2; ++ks) {
                const bf16x8 wb = cvt8(w[cur][ks][0], w[cur][ks][1]);
                #pragma unroll
                for (int m = 0; m < 4; ++m)
                    acc[m] = __builtin_amdgcn_mfma_f32_16x16x32_bf16(
                                 a[cur][m][ks], wb, acc[m], 0, 0, 0);
            }
        }
    }

    // bias along output column j = wv*H + hc0 + (lane&15)  (C/D col = lane&15)
    const float bias = bih[wv * HD + hc0 + ar] + bhh[wv * HD + hc0 + ar];

    __shared__ float Sg[4][64][17];   // [gate][batch][hcol], padded
    #pragma unroll
    for (int m = 0; m < 4; ++m)
        #pragma unroll
        for (int r = 0; r < 4; ++r)   // D row = m*16 + kg*4 + r
            Sg[wv][m * 16 + kg * 4 + r][ar] = acc[m][r] + bias;
    __syncthreads();

    #pragma unroll
    for (int p = 0; p < 4; ++p) {
        const int idx = tid + p * 256;        // 1024 (b, hcol) pairs
        const int b = idx >> 4, hc = idx & 15;
        const float ig = Sg[0][b][hc], fg = Sg[1][b][hc];
        const float gg = Sg[2][b][hc], og = Sg[3][b][hc];
        const long off = (long)b * HD + hc0 + hc;
        const float co = cprev[off];
        const float cn = sigmoidf_(fg) * co + sigmoidf_(ig) * tanhf(gg);
        const float hn = sigmoidf_(og) * tanhf(cn);
        hout[off] = hn;
        cout[off] = cn;
        if (hout2) hout2[off] = hn;
        hbf[off] = f2bf(hn);
    }
}

// ---------------------------------------------------------------------------
// Head layer 1: hid = relu(h2 @ Wc1^T + bc1). N=2048, K=4096.
// grid 128 x 256. Block owns 16 output cols; 4 waves split K (1024 each),
// partials reduced through LDS.
// ---------------------------------------------------------------------------
__global__ __launch_bounds__(256, 1) void head_kernel(
    const short* __restrict__ Abf, const float* __restrict__ Wc1,
    const float* __restrict__ bc1, float* __restrict__ hid)
{
    const int tid = threadIdx.x, lane = tid & 63, wv = tid >> 6;
    const int ar = lane & 15, kg = lane >> 4;
    const int n0 = blockIdx.x * 16;

    const short* pa = Abf + (long)ar * HD + wv * 1024 + kg * 8;
    const float* pw = Wc1 + (long)(n0 + ar) * HD + wv * 1024 + kg * 8;

    const f32x4 zero = {0.f, 0.f, 0.f, 0.f};
    f32x4 acc[4] = {zero, zero, zero, zero};
    bf16x8 a[2][4][2];
    f32x4  w[2][2][2];

    #pragma unroll
    for (int m = 0; m < 4; ++m)
        #pragma unroll
        for (int ks = 0; ks < 2; ++ks)
            a[0][m][ks] = *(const bf16x8*)(pa + m * 16 * HD + ks * 32);
    #pragma unroll
    for (int ks = 0; ks < 2; ++ks) {
        w[0][ks][0] = *(const f32x4*)(pw + ks * 32);
        w[0][ks][1] = *(const f32x4*)(pw + ks * 32 + 4);
    }

    #pragma unroll 2
    for (int t = 0; t < 16; ++t) {           // 1024 K per wave
        const int cur = t & 1, nxt = cur ^ 1;
        if (t < 15) {
            const int ko = (t + 1) * 64;
            #pragma unroll
            for (int m = 0; m < 4; ++m)
                #pragma unroll
                for (int ks = 0; ks < 2; ++ks)
                    a[nxt][m][ks] = *(const bf16x8*)(pa + m * 16 * HD + ko + ks * 32);
            #pragma unroll
            for (int ks = 0; ks < 2; ++ks) {
                w[nxt][ks][0] = *(const f32x4*)(pw + ko + ks * 32);
                w[nxt][ks][1] = *(const f32x4*)(pw + ko + ks * 32 + 4);
            }
        }
        #pragma unroll
        for (int ks = 0; ks < 2; ++ks) {
            const bf16x8 wb = cvt8(w[cur][ks][0], w[cur][ks][1]);
            #pragma unroll
            for (int m = 0; m < 4; ++m)
                acc[m] = __builtin_amdgcn_mfma_f32_16x16x32_bf16(
                             a[cur][m][ks], wb, acc[m], 0, 0, 0);
        }
    }

    __shared__ float Sg[4][64][17];  // [k-quarter][batch][col]
    #pragma unroll
    for (int m = 0; m < 4; ++m)
        #pragma unroll
        for (int r = 0; r < 4; ++r)
            Sg[wv][m * 16 + kg * 4 + r][ar] = acc[m][r];
    __syncthreads();

    #pragma unroll
    for (int p = 0; p < 4; ++p) {
        const int idx = tid + p * 256;
        const int b = idx >> 4, hc = idx & 15;
        const float v = Sg[0][b][hc] + Sg[1][b][hc] + Sg[2][b][hc] + Sg[3][b][hc]
                      + bc1[n0 + hc];
        hid[(long)b * 2048 + n0 + hc] = fmaxf(v, 0.f);
    }
}

// ---------------------------------------------------------------------------
// Head layer 2: count = relu(hid @ Wc2^T + bc2). [64,2048] x [2048] -> [64].
// One block, 4 threads per row, shuffle-combine.
// ---------------------------------------------------------------------------
__global__ void count_kernel(const float* __restrict__ hid, const float* __restrict__ Wc2,
                             const float* __restrict__ bc2, float* __restrict__ out)
{
    const int tid = threadIdx.x;
    const int b = tid >> 2, q = tid & 3;
    const float* hp = hid + (long)b * 2048 + q * 512;
    const float* wp = Wc2 + q * 512;
    float s = 0.f;
    #pragma unroll 4
    for (int k = 0; k < 512; k += 4) {
        f32x4 h4 = *(const f32x4*)(hp + k);
        f32x4 w4 = *(const f32x4*)(wp + k);
        s += h4[0] * w4[0] + h4[1] * w4[1] + h4[2] * w4[2] + h4[3] * w4[3];
    }
    s += __shfl_xor(s, 1);
    s += __shfl_xor(s, 2);
    if (q == 0) out[b] = fmaxf(s + bc2[0], 0.f);
}

// ---------------------------------------------------------------------------
extern "C" void kernel_launch(void* const* d_in, const int* in_sizes, int n_in,
                              void* d_out, int out_size, void* d_ws, size_t ws_size,
                              hipStream_t stream)
{
    const float* X    = (const float*)d_in[0];
    const float* h0   = (const float*)d_in[1];
    const float* c0   = (const float*)d_in[2];
    const float* Wih0 = (const float*)d_in[3];
    const float* Whh0 = (const float*)d_in[4];
    const float* bih0 = (const float*)d_in[5];
    const float* bhh0 = (const float*)d_in[6];
    const float* Wih1 = (const float*)d_in[7];
    const float* Whh1 = (const float*)d_in[8];
    const float* bih1 = (const float*)d_in[9];
    const float* bhh1 = (const float*)d_in[10];
    const float* Wc1  = (const float*)d_in[11];
    const float* bc1  = (const float*)d_in[12];
    const float* Wc2  = (const float*)d_in[13];
    const float* bc2  = (const float*)d_in[14];

    float* out  = (float*)d_out;
    float* ms   = out;                  // memory_state [64][4096]
    float* hnew = out + 262144;         // h_new [2][64][4096]
    float* cnew = out + 786432;         // c_new [2][64][4096]
    float* cnt  = out + 1310720;        // count [64]

    char* ws = (char*)d_ws;
    short* Xbf  = (short*)ws;                       // 512 KB
    short* H0bf = (short*)(ws + 524288);            // 1 MB ([2][64][4096] bf16)
    short* h1bf = (short*)(ws + 1572864);           // 512 KB
    short* h2bf = (short*)(ws + 2097152);           // 512 KB
    float* hid  = (float*)(ws + 2621440);           // 512 KB ([64][2048] fp32)

    hipLaunchKernelGGL(convert_kernel, dim3(768), dim3(256), 0, stream, X, h0, Xbf, H0bf);

    hipLaunchKernelGGL(lstm_layer_kernel, dim3(256), dim3(256), 0, stream,
                       Xbf, H0bf, Wih0, Whh0, bih0, bhh0, c0,
                       hnew, cnew, (float*)nullptr, h1bf);

    hipLaunchKernelGGL(lstm_layer_kernel, dim3(256), dim3(256), 0, stream,
                       h1bf, H0bf + 262144, Wih1, Whh1, bih1, bhh1, c0 + 262144,
                       hnew + 262144, cnew + 262144, ms, h2bf);

    hipLaunchKernelGGL(head_kernel, dim3(128), dim3(256), 0, stream, h2bf, Wc1, bc1, hid);
    hipLaunchKernelGGL(count_kernel, dim3(1), dim3(256), 0, stream, hid, Wc2, bc2, cnt);
}

// Round 2
// 383.769 us; speedup vs baseline: 1.0781x; 1.0781x over previous
//
#include <hip/hip_runtime.h>

#define HD 4096

typedef __attribute__((ext_vector_type(4))) float f32x4;
typedef __attribute__((ext_vector_type(8))) short bf16x8;
typedef __attribute__((ext_vector_type(4))) short s16x4;

__device__ __forceinline__ short f2bf(float f) {
    unsigned u = __float_as_uint(f);
    u += 0x7fffu + ((u >> 16) & 1u);   // RNE (finite inputs)
    return (short)(u >> 16);
}

// 8x fp32 -> 8x bf16 via v_cvt_pk_bf16_f32 (2 elems/instr, RNE)
__device__ __forceinline__ bf16x8 cvt8pk(f32x4 lo, f32x4 hi) {
    union { bf16x8 v; unsigned u[4]; } r;
    asm("v_cvt_pk_bf16_f32 %0, %1, %2" : "=v"(r.u[0]) : "v"(lo[0]), "v"(lo[1]));
    asm("v_cvt_pk_bf16_f32 %0, %1, %2" : "=v"(r.u[1]) : "v"(lo[2]), "v"(lo[3]));
    asm("v_cvt_pk_bf16_f32 %0, %1, %2" : "=v"(r.u[2]) : "v"(hi[0]), "v"(hi[1]));
    asm("v_cvt_pk_bf16_f32 %0, %1, %2" : "=v"(r.u[3]) : "v"(hi[2]), "v"(hi[3]));
    return r.v;
}

__device__ __forceinline__ void gl_lds16(const float* g, float* l) {
    typedef const __attribute__((address_space(1))) void* gas_t;
    typedef __attribute__((address_space(3))) void* las_t;
    __builtin_amdgcn_global_load_lds((gas_t)(const void*)g, (las_t)(void*)l, 16, 0, 0);
}

__device__ __forceinline__ float sigmoidf_(float x) { return 1.f / (1.f + __expf(-x)); }

// ---------------------------------------------------------------------------
// fp32 activations -> bf16. X: 65536 f32x4, h0: 131072 f32x4. Grid 768x256.
// ---------------------------------------------------------------------------
__global__ void convert_kernel(const float* __restrict__ X, const float* __restrict__ h0,
                               short* __restrict__ Xbf, short* __restrict__ H0bf)
{
    const int i = blockIdx.x * blockDim.x + threadIdx.x;
    if (i < 65536) {
        f32x4 v = ((const f32x4*)X)[i];
        s16x4 o = { f2bf(v[0]), f2bf(v[1]), f2bf(v[2]), f2bf(v[3]) };
        ((s16x4*)Xbf)[i] = o;
    } else {
        const int j = i - 65536;
        f32x4 v = ((const f32x4*)h0)[j];
        s16x4 o = { f2bf(v[0]), f2bf(v[1]), f2bf(v[2]), f2bf(v[3]) };
        ((s16x4*)H0bf)[j] = o;
    }
}

// ---------------------------------------------------------------------------
// Partial GEMM: P[kq][64][N] = A(bf16)[64][K-slice] @ W(fp32)^T.
// grid = (N/64) * nkq blocks x 256 thr. block: 64 cols x K-slice KB.
// wave wv: 16 cols (n0w..+16), full block K-slice. K split in two source
// halves (A0/W0 then A1/W1), each of size Khalf = KB*nkq/2.
// W staged via global_load_lds into wave-private LDS dbuf (no barriers),
// counted vmcnt(12); LDS granule-swizzled on the GLOBAL source (rule #21).
// ---------------------------------------------------------------------------
#define STAGE(LB, TT) \
    _Pragma("unroll") for (int i_ = 0; i_ < 4; ++i_) \
        gl_lds16(wsrc[i_] + (TT) * 64, (LB) + i_ * 256);

#define ALOAD(BUF, TT) \
    _Pragma("unroll") for (int m_ = 0; m_ < 4; ++m_) \
    _Pragma("unroll") for (int ks_ = 0; ks_ < 2; ++ks_) \
        a[BUF][m_][ks_] = *(const bf16x8*)(aBase + m_ * 16 * HD + (TT) * 64 + ks_ * 32);

#define COMP(LB, BUF) \
    _Pragma("unroll") for (int ks_ = 0; ks_ < 2; ++ks_) { \
        const int bofs_ = ar * 64 + ks_ * 32; \
        f32x4 wlo_ = *(const f32x4*)((LB) + bofs_ + ((((kg * 2)    ) ^ (ar & 7)) << 2)); \
        f32x4 whi_ = *(const f32x4*)((LB) + bofs_ + ((((kg * 2) + 1) ^ (ar & 7)) << 2)); \
        bf16x8 wb_ = cvt8pk(wlo_, whi_); \
        _Pragma("unroll") for (int m_ = 0; m_ < 4; ++m_) \
            acc[m_] = __builtin_amdgcn_mfma_f32_16x16x32_bf16(a[BUF][m_][ks_], wb_, acc[m_], 0, 0, 0); \
    }

__global__ __launch_bounds__(256, 4) void gemm_part_kernel(
    const short* __restrict__ A0, const short* __restrict__ A1,
    const float* __restrict__ W0, const float* __restrict__ W1,
    float* __restrict__ P, int N, int nkq, int KB)
{
    __shared__ float wlds[4][2][1024];   // [wave][buf][16 rows x 64 k] = 32 KB
    const int tid = threadIdx.x, lane = tid & 63, wv = tid >> 6;
    const int ar = lane & 15, kg = lane >> 4;
    const int bid = blockIdx.x;
    const int ntile = bid / nkq, kq = bid % nkq;
    const int half = nkq >> 1;
    const int kqh = (kq >= half) ? 1 : 0;
    const int kqi = kq - kqh * half;
    const short* A = kqh ? A1 : A0;
    const float* W = kqh ? W1 : W0;
    const int kbase = kqi * KB;          // float/short offset within the half
    const int T = KB >> 6;
    const int n0w = ntile * 64 + wv * 16;

    // A fragment base: row (m*16 + ar), k = kbase + kg*8
    const short* aBase = A + (long)ar * HD + kbase + kg * 8;

    // global_load_lds sources: instr i covers LDS rows i*4 + (lane>>4);
    // within-row 16B granule q = lane&15 holds logical granule q ^ (row&7).
    const float* wsrc[4];
    #pragma unroll
    for (int i = 0; i < 4; ++i) {
        const int row = i * 4 + kg;
        wsrc[i] = W + (long)(n0w + row) * HD + kbase + (((lane & 15) ^ (row & 7)) << 2);
    }
    float* lb0 = &wlds[wv][0][0];
    float* lb1 = &wlds[wv][1][0];

    const f32x4 zero = {0.f, 0.f, 0.f, 0.f};
    f32x4 acc[4] = {zero, zero, zero, zero};
    bf16x8 a[2][4][2];

    STAGE(lb0, 0); ALOAD(0, 0);
    const int T2 = T >> 1;
    for (int u = 0; u < T2; ++u) {
        const int t0 = u * 2, t1 = t0 + 1;
        STAGE(lb1, t1); ALOAD(1, t1);
        asm volatile("s_waitcnt vmcnt(12)" ::: "memory");
        __builtin_amdgcn_sched_barrier(0);
        COMP(lb0, 0);
        if (u + 1 < T2) {
            STAGE(lb0, t0 + 2); ALOAD(0, t0 + 2);
            asm volatile("s_waitcnt vmcnt(12)" ::: "memory");
        } else {
            asm volatile("s_waitcnt vmcnt(0)" ::: "memory");
        }
        __builtin_amdgcn_sched_barrier(0);
        COMP(lb1, 1);
    }

    // write partial: P[kq][row][col], row = m*16 + kg*4 + r, col = n0w + ar
    float* pr = P + (long)kq * 64 * N + n0w + ar;
    #pragma unroll
    for (int m = 0; m < 4; ++m)
        #pragma unroll
        for (int r = 0; r < 4; ++r)
            pr[(long)(m * 16 + kg * 4 + r) * N] = acc[m][r];
}

// ---------------------------------------------------------------------------
// Reduce nkq partials + biases + LSTM cell. 65536 threads, f32x4 per thread.
// P layout: [nkq][64][16384], gates i,f,g,o at col g*4096 + hc.
// ---------------------------------------------------------------------------
__global__ void cell_kernel(const float* __restrict__ P, int nkq,
                            const float* __restrict__ bi, const float* __restrict__ bh,
                            const float* __restrict__ cprev,
                            float* __restrict__ hout, float* __restrict__ cout,
                            float* __restrict__ ms, short* __restrict__ hbf)
{
    const int idx = blockIdx.x * blockDim.x + threadIdx.x;  // 0..65535
    const int b = idx >> 10;
    const int hc = (idx & 1023) * 4;

    f32x4 g[4] = {{0,0,0,0},{0,0,0,0},{0,0,0,0},{0,0,0,0}};
    for (int kq = 0; kq < nkq; ++kq) {
        const float* pb = P + ((long)kq * 64 + b) * 16384 + hc;
        #pragma unroll
        for (int gt = 0; gt < 4; ++gt)
            g[gt] += *(const f32x4*)(pb + gt * 4096);
    }
    #pragma unroll
    for (int gt = 0; gt < 4; ++gt) {
        g[gt] += *(const f32x4*)(bi + gt * HD + hc);
        g[gt] += *(const f32x4*)(bh + gt * HD + hc);
    }
    const long off = (long)b * HD + hc;
    f32x4 c = *(const f32x4*)(cprev + off);
    f32x4 hn, cn; s16x4 hb;
    #pragma unroll
    for (int e = 0; e < 4; ++e) {
        float cv = sigmoidf_(g[1][e]) * c[e] + sigmoidf_(g[0][e]) * tanhf(g[2][e]);
        float hv = sigmoidf_(g[3][e]) * tanhf(cv);
        cn[e] = cv; hn[e] = hv; hb[e] = f2bf(hv);
    }
    *(f32x4*)(hout + off) = hn;
    *(f32x4*)(cout + off) = cn;
    if (ms) *(f32x4*)(ms + off) = hn;
    *(s16x4*)(hbf + off) = hb;
}

// ---------------------------------------------------------------------------
// Head finish: hid[b][n] = relu(sum_kq P[kq][b][n] + bc1[n]). N=2048.
// ---------------------------------------------------------------------------
__global__ void headfin_kernel(const float* __restrict__ P, int nkq,
                               const float* __restrict__ bc1, float* __restrict__ hid)
{
    const int idx = blockIdx.x * blockDim.x + threadIdx.x;  // 0..32767
    const int b = idx >> 9;
    const int n = (idx & 511) * 4;
    f32x4 s = {0.f, 0.f, 0.f, 0.f};
    for (int kq = 0; kq < nkq; ++kq)
        s += *(const f32x4*)(P + ((long)kq * 64 + b) * 2048 + n);
    s += *(const f32x4*)(bc1 + n);
    #pragma unroll
    for (int e = 0; e < 4; ++e) s[e] = fmaxf(s[e], 0.f);
    *(f32x4*)(hid + (long)b * 2048 + n) = s;
}

// ---------------------------------------------------------------------------
// count = relu(hid @ Wc2^T + bc2). [64,2048] x [2048] -> [64].
// ---------------------------------------------------------------------------
__global__ void count_kernel(const float* __restrict__ hid, const float* __restrict__ Wc2,
                             const float* __restrict__ bc2, float* __restrict__ out)
{
    const int tid = threadIdx.x;
    const int b = tid >> 2, q = tid & 3;
    const float* hp = hid + (long)b * 2048 + q * 512;
    const float* wp = Wc2 + q * 512;
    float s = 0.f;
    #pragma unroll 4
    for (int k = 0; k < 512; k += 4) {
        f32x4 h4 = *(const f32x4*)(hp + k);
        f32x4 w4 = *(const f32x4*)(wp + k);
        s += h4[0] * w4[0] + h4[1] * w4[1] + h4[2] * w4[2] + h4[3] * w4[3];
    }
    s += __shfl_xor(s, 1);
    s += __shfl_xor(s, 2);
    if (q == 0) out[b] = fmaxf(s + bc2[0], 0.f);
}

// ---------------------------------------------------------------------------
extern "C" void kernel_launch(void* const* d_in, const int* in_sizes, int n_in,
                              void* d_out, int out_size, void* d_ws, size_t ws_size,
                              hipStream_t stream)
{
    const float* X    = (const float*)d_in[0];
    const float* h0   = (const float*)d_in[1];
    const float* c0   = (const float*)d_in[2];
    const float* Wih0 = (const float*)d_in[3];
    const float* Whh0 = (const float*)d_in[4];
    const float* bih0 = (const float*)d_in[5];
    const float* bhh0 = (const float*)d_in[6];
    const float* Wih1 = (const float*)d_in[7];
    const float* Whh1 = (const float*)d_in[8];
    const float* bih1 = (const float*)d_in[9];
    const float* bhh1 = (const float*)d_in[10];
    const float* Wc1  = (const float*)d_in[11];
    const float* bc1  = (const float*)d_in[12];
    const float* Wc2  = (const float*)d_in[13];
    const float* bc2  = (const float*)d_in[14];

    float* out  = (float*)d_out;
    float* ms   = out;                  // memory_state [64][4096]
    float* hnew = out + 262144;         // h_new [2][64][4096]
    float* cnew = out + 786432;         // c_new [2][64][4096]
    float* cnt  = out + 1310720;        // count [64]

    char* ws = (char*)d_ws;
    short* Xbf  = (short*)ws;                       // 512 KB
    short* H0bf = (short*)(ws + (1u << 19));        // 1 MB
    short* h1bf = (short*)(ws + 3u * (1u << 19));   // 512 KB
    short* h2bf = (short*)(ws + (1u << 21));        // 512 KB
    float* hid  = (float*)(ws + 5u * (1u << 19));   // 512 KB
    float* Pp   = (float*)(ws + 3u * (1u << 20));   // up to 16 MB partials

    // K-split: 4 (16 MB partials) if ws allows, else 2 (8 MB)
    const int nkq = (ws_size >= (3u + 16u) * (1u << 20)) ? 4 : 2;
    const int KBl = (nkq == 4) ? 2048 : 4096;       // per-block K-slice (layer)

    hipLaunchKernelGGL(convert_kernel, dim3(768), dim3(256), 0, stream, X, h0, Xbf, H0bf);

    hipLaunchKernelGGL(gemm_part_kernel, dim3(256 * nkq), dim3(256), 0, stream,
                       Xbf, H0bf, Wih0, Whh0, Pp, 16384, nkq, KBl);
    hipLaunchKernelGGL(cell_kernel, dim3(256), dim3(256), 0, stream,
                       Pp, nkq, bih0, bhh0, c0, hnew, cnew, (float*)nullptr, h1bf);

    hipLaunchKernelGGL(gemm_part_kernel, dim3(256 * nkq), dim3(256), 0, stream,
                       h1bf, H0bf + 262144, Wih1, Whh1, Pp, 16384, nkq, KBl);
    hipLaunchKernelGGL(cell_kernel, dim3(256), dim3(256), 0, stream,
                       Pp, nkq, bih1, bhh1, c0 + 262144, hnew + 262144, cnew + 262144, ms, h2bf);

    // head: N=2048, K=4096 -> halves of 2048, nkq=8, KB=512, grid 256
    hipLaunchKernelGGL(gemm_part_kernel, dim3(32 * 8), dim3(256), 0, stream,
                       h2bf, h2bf + 2048, Wc1, Wc1 + 2048, Pp, 2048, 8, 512);
    hipLaunchKernelGGL(headfin_kernel, dim3(128), dim3(256), 0, stream, Pp, 8, bc1, hid);
    hipLaunchKernelGGL(count_kernel, dim3(1), dim3(256), 0, stream, hid, Wc2, bc2, cnt);
}